// Round 22
// baseline (106.647 us; speedup 1.0000x reference)
//
#include <hip/hip_runtime.h>

#define N_ROWS 4096
#define D_K    2048
#define BP   128                      // panel size
#define NPAN (N_ROWS / BP)            // 32 panels
#define NTRI (NPAN * (NPAN + 1) / 2)  // 528 triangle tiles
#define BK   32
#define NT   (D_K / BK)               // 64 K-tiles
#define MARGIN 0.3f

typedef unsigned short u16;
typedef __attribute__((ext_vector_type(8))) short bf16x8;
typedef __attribute__((ext_vector_type(4))) float f32x4;

__device__ __forceinline__ void stage16(const u16* src, u16* dst) {
    __builtin_amdgcn_global_load_lds((const __attribute__((address_space(1))) unsigned int*)src,
                                     (__attribute__((address_space(3))) unsigned int*)dst, 16, 0, 0);
}

__device__ __forceinline__ u16 f2bf(float f) {
    unsigned u = __float_as_uint(f);
    u += 0x7fffu + ((u >> 16) & 1u);   // round-to-nearest-even
    return (u16)(u >> 16);
}

// ---------- Kernel 1: fp32 -> bf16 convert, exact fp32 row norms, init ap2/an2 ----------
__global__ __launch_bounds__(256) void prep_kernel(
    const float* __restrict__ emb, u16* __restrict__ embB,
    float* __restrict__ xx, unsigned* __restrict__ ap2, unsigned* __restrict__ an2)
{
    const int row = blockIdx.x;
    const int t = threadIdx.x;
    const float4* src = (const float4*)(emb + (size_t)row * D_K);
    ushort4* dst = (ushort4*)(embB + (size_t)row * D_K);
    float s = 0.f;
#pragma unroll
    for (int i = 0; i < 2; ++i) {
        float4 v = src[t + i * 256];
        s = fmaf(v.x, v.x, s);
        s = fmaf(v.y, v.y, s);
        s = fmaf(v.z, v.z, s);
        s = fmaf(v.w, v.w, s);
        ushort4 o;
        o.x = f2bf(v.x); o.y = f2bf(v.y); o.z = f2bf(v.z); o.w = f2bf(v.w);
        dst[t + i * 256] = o;
    }
#pragma unroll
    for (int off = 32; off >= 1; off >>= 1) s += __shfl_down(s, off, 64);
    __shared__ float red[4];
    if ((t & 63) == 0) red[t >> 6] = s;
    __syncthreads();
    if (t == 0) {
        xx[row] = red[0] + red[1] + red[2] + red[3];
        ap2[row] = 0u;            // float 0.0
        an2[row] = 0x7f7fffffu;   // FLT_MAX
    }
}

// ---------- Kernel 2: triangle 128x128, dbuf BK=32, READS-FIRST region, dual-reduction ----------
#define LDv(p) (*(const bf16x8*)(p))

// Stage one K-tile into buffer B_ (LITERAL 0/1); offsets in u16 elements (buf stride 4096).
#define STAGE32(B_, KO_) do {                          \
    stage16(gA0 + (KO_), lA + (B_) * 4096);            \
    stage16(gA1 + (KO_), lA + (B_) * 4096 + 2048);     \
    stage16(gB0 + (KO_), lB + (B_) * 4096);            \
    stage16(gB1 + (KO_), lB + (B_) * 4096 + 2048);     \
} while (0)

// One K-tile, READS FIRST: frag ds_reads(t from CB_) -> stage(t+1 -> NB_) -> 16 MFMA -> sync.
// No LDS-write precedes the LDS-reads in-region, so no conservative vmcnt drain lands
// before them; the sync's vmcnt(0) drain of stage(t+1) is covered by the MFMA cluster.
#define KT(CB_, NB_, T_)                                                              \
  {                                                                                   \
    bf16x8 aq[4], bq[4];                                                              \
    _Pragma("unroll")                                                                 \
    for (int m = 0; m < 4; ++m) aq[m] = LDv(AB + (CB_) * 8192 + aOff + m * 1024 + kx);\
    _Pragma("unroll")                                                                 \
    for (int n = 0; n < 4; ++n) bq[n] = LDv(BB + (CB_) * 8192 + bOff + n * 1024 + kx);\
    if ((T_) + 1 < NT) { STAGE32(NB_, ((T_) + 1) * BK); }                             \
    _Pragma("unroll")                                                                 \
    for (int m = 0; m < 4; ++m)                                                       \
        _Pragma("unroll")                                                             \
        for (int n = 0; n < 4; ++n)                                                   \
            acc[m][n] = __builtin_amdgcn_mfma_f32_16x16x32_bf16(aq[m], bq[n], acc[m][n], 0, 0, 0); \
    __syncthreads();                                                                  \
  }

__global__ __launch_bounds__(256) void gram_tri_kernel(
    const u16* __restrict__ embB, const float* __restrict__ xx,
    const int* __restrict__ lab, unsigned* __restrict__ ap2, unsigned* __restrict__ an2)
{
    __shared__ u16 As[2 * BP * BK];   // 16 KiB: [buf][128 rows][32 cols], 16B-slot swizzled
    __shared__ u16 Bs[2 * BP * BK];   // 16 KiB
    __shared__ int labR[BP], labC[BP];
    __shared__ float xxR[BP], xxC[BP];

    const int tid = threadIdx.x;

    // XCD-aware bijective swizzle (528 = 66 * 8), then triangle unrank (I <= J)
    const int bid = blockIdx.x;
    const int p = (bid & 7) * (NTRI / 8) + (bid >> 3);
    int I = 0, rem = p;
    while (rem >= NPAN - I) { rem -= NPAN - I; ++I; }
    const int J = I + rem;
    const int row0 = I * BP, col0 = J * BP;
    const bool diag = (I == J);

    // ---- staging: linear LDS dest (tid*16B), pre-swizzled global source.
    // Row = 64B = 4 slots; involution: slot ^= (row>>1)&3  (r7/r11-verified, 0 conflicts)
    const int csw = ((tid & 3) ^ ((tid >> 3) & 3)) * 8;   // u16 elements
    const int srow = tid >> 2;                            // 0..63
    const u16* gA0 = embB + (size_t)(row0 + srow) * D_K + csw;
    const u16* gA1 = embB + (size_t)(row0 + 64 + srow) * D_K + csw;
    const u16* gB0 = embB + (size_t)(col0 + srow) * D_K + csw;
    const u16* gB1 = embB + (size_t)(col0 + 64 + srow) * D_K + csw;
    u16* lA = As + tid * 8;
    u16* lB = Bs + tid * 8;

    // ---- fragment constants: 2x2 waves, wave (wr,wc) owns rows wr*64+.., cols wc*64+..
    const int l = tid & 63, w = tid >> 6;
    const int wr = w >> 1, wc = w & 1;
    const int fr = l & 15, fkb = l >> 4;            // frag row / k-slot
    const int kx = (fkb ^ ((fr >> 1) & 3)) * 16;    // swizzled 16B slot within 64B row (bytes)
    const char* AB = (const char*)As;
    const char* BB = (const char*)Bs;
    const int aOff = wr * 4096 + fr * 64;           // + buf*8192 + m*1024 (bytes)
    const int bOff = wc * 4096 + fr * 64;           // + buf*8192 + n*1024 (bytes)

    f32x4 acc[4][4];
#pragma unroll
    for (int m = 0; m < 4; ++m)
#pragma unroll
        for (int n = 0; n < 4; ++n) acc[m][n] = (f32x4){0.f, 0.f, 0.f, 0.f};

    // ---- prologue: tile 0 -> buf0; sync drains it
    STAGE32(0, 0);
    __syncthreads();

    // ---- main loop: 2 K-tiles per iteration, buf index as compile-time literal
    for (int ii = 0; ii < NT / 2; ++ii) {
        const int t2 = 2 * ii;
        KT(0, 1, t2)
        KT(1, 0, t2 + 1)
    }

    // ---- epilogue metadata
    if (tid < BP)      { labR[tid] = lab[row0 + tid]; xxR[tid] = xx[row0 + tid]; }
    else               { int u2 = tid - BP; labC[u2] = lab[col0 + u2]; xxC[u2] = xx[col0 + u2]; }
    __syncthreads();

    const int rgrp = l >> 4;

    // ---- ROW pass: output rows = panel I; reduce over this tile's 128 cols
    // C/D: row = m*16 + rgrp*4 + r (+wr*64), col = n*16 + fr (+wc*64)
#pragma unroll
    for (int m = 0; m < 4; ++m) {
#pragma unroll
        for (int r = 0; r < 4; ++r) {
            const int il = wr * 64 + m * 16 + rgrp * 4 + r;
            const int li = labR[il];
            const float xi = xxR[il];
            float apv = 0.f, anv = __FLT_MAX__;
#pragma unroll
            for (int n = 0; n < 4; ++n) {
                const int jl = wc * 64 + n * 16 + fr;
                float d2 = xi + xxC[jl] - 2.f * acc[m][n][r];
                d2 = fmaxf(d2, 1e-12f);
                const bool same = (labC[jl] == li);
                apv = same ? fmaxf(apv, d2) : apv;
                anv = same ? anv : fminf(anv, d2);
            }
#pragma unroll
            for (int off = 1; off < 16; off <<= 1) {   // fold 16 fr-lanes (in-group)
                apv = fmaxf(apv, __shfl_xor(apv, off, 64));
                anv = fminf(anv, __shfl_xor(anv, off, 64));
            }
            if (fr == 0) {
                atomicMax(&ap2[row0 + il], __float_as_uint(apv));
                atomicMin(&an2[row0 + il], __float_as_uint(anv));
            }
        }
    }

    // ---- COL pass (off-diagonal tiles only): output rows = panel J; reduce over tile's 128 rows
    if (!diag) {
#pragma unroll
        for (int n = 0; n < 4; ++n) {
            const int jl = wc * 64 + n * 16 + fr;
            const int lj = labC[jl];
            const float xj = xxC[jl];
            float apv = 0.f, anv = __FLT_MAX__;
#pragma unroll
            for (int m = 0; m < 4; ++m) {
#pragma unroll
                for (int r = 0; r < 4; ++r) {
                    const int il = wr * 64 + m * 16 + rgrp * 4 + r;
                    float d2 = xj + xxR[il] - 2.f * acc[m][n][r];
                    d2 = fmaxf(d2, 1e-12f);
                    const bool same = (labR[il] == lj);
                    apv = same ? fmaxf(apv, d2) : apv;
                    anv = same ? anv : fminf(anv, d2);
                }
            }
            // fold rgrp groups (lanes differ in bits 4-5; fr/col preserved)
            apv = fmaxf(apv, __shfl_xor(apv, 16, 64));
            anv = fminf(anv, __shfl_xor(anv, 16, 64));
            apv = fmaxf(apv, __shfl_xor(apv, 32, 64));
            anv = fminf(anv, __shfl_xor(anv, 32, 64));
            if (rgrp == 0) {   // one lane per col per wave; both wr waves merge via atomics
                atomicMax(&ap2[col0 + jl], __float_as_uint(apv));
                atomicMin(&an2[col0 + jl], __float_as_uint(anv));
            }
        }
    }
}

// ---------- Kernel 3: finalize loss + precision ----------
__global__ __launch_bounds__(256) void finalize_kernel(
    const unsigned* __restrict__ ap2, const unsigned* __restrict__ an2, float* __restrict__ out)
{
    const int t = threadIdx.x;
    float ls = 0.f, ps = 0.f;
    for (int i = t; i < N_ROWS; i += 256) {
        const float ap = sqrtf(__uint_as_float(ap2[i]));
        const float an = sqrtf(__uint_as_float(an2[i]));
        ls += fmaxf(MARGIN - an + ap, 0.f);
        ps += (an > ap) ? 1.f : 0.f;
    }
#pragma unroll
    for (int off = 32; off >= 1; off >>= 1) {
        ls += __shfl_down(ls, off, 64);
        ps += __shfl_down(ps, off, 64);
    }
    __shared__ float rl[4], rp[4];
    if ((t & 63) == 0) { rl[t >> 6] = ls; rp[t >> 6] = ps; }
    __syncthreads();
    if (t == 0) {
        out[0] = (rl[0] + rl[1] + rl[2] + rl[3]) * (1.f / N_ROWS);
        out[1] = (rp[0] + rp[1] + rp[2] + rp[3]) * (1.f / N_ROWS);
    }
}

extern "C" void kernel_launch(void* const* d_in, const int* in_sizes, int n_in,
                              void* d_out, int out_size, void* d_ws, size_t ws_size,
                              hipStream_t stream)
{
    const float* emb = (const float*)d_in[0];
    const int* lab = (const int*)d_in[1];
    float* out = (float*)d_out;

    char* ws = (char*)d_ws;
    u16* embB   = (u16*)ws;                                           // 16 MB
    float* xx   = (float*)(ws + (size_t)N_ROWS * D_K * 2);
    unsigned* ap2 = (unsigned*)(ws + (size_t)N_ROWS * D_K * 2 + N_ROWS * 4);
    unsigned* an2 = (unsigned*)(ws + (size_t)N_ROWS * D_K * 2 + 2 * (size_t)N_ROWS * 4);

    prep_kernel<<<N_ROWS, 256, 0, stream>>>(emb, embB, xx, ap2, an2);
    gram_tri_kernel<<<NTRI, 256, 0, stream>>>(embB, xx, lab, ap2, an2);   // 528 blocks
    finalize_kernel<<<1, 256, 0, stream>>>(ap2, an2, out);
}

// Round 23
// 74.523 us; speedup vs baseline: 1.4311x; 1.4311x over previous
//
#include <hip/hip_runtime.h>

#define N_ROWS 4096
#define D_K    2048
#define BP   128                      // panel size
#define NPAN (N_ROWS / BP)            // 32 panels
#define NTRI (NPAN * (NPAN + 1) / 2)  // 528 triangle tiles
#define BK   32
#define NT   (D_K / BK)               // 64 K-tiles
#define MARGIN 0.3f

typedef unsigned short u16;
typedef __attribute__((ext_vector_type(8))) short bf16x8;
typedef __attribute__((ext_vector_type(4))) float f32x4;

__device__ __forceinline__ void stage16(const u16* src, u16* dst) {
    __builtin_amdgcn_global_load_lds((const __attribute__((address_space(1))) unsigned int*)src,
                                     (__attribute__((address_space(3))) unsigned int*)dst, 16, 0, 0);
}

__device__ __forceinline__ u16 f2bf(float f) {
    unsigned u = __float_as_uint(f);
    u += 0x7fffu + ((u >> 16) & 1u);   // round-to-nearest-even
    return (u16)(u >> 16);
}

// ---------- Kernel 1: fp32 -> bf16 convert, exact fp32 row norms, init ap2/an2 ----------
__global__ __launch_bounds__(256) void prep_kernel(
    const float* __restrict__ emb, u16* __restrict__ embB,
    float* __restrict__ xx, unsigned* __restrict__ ap2, unsigned* __restrict__ an2)
{
    const int row = blockIdx.x;
    const int t = threadIdx.x;
    const float4* src = (const float4*)(emb + (size_t)row * D_K);
    ushort4* dst = (ushort4*)(embB + (size_t)row * D_K);
    float s = 0.f;
#pragma unroll
    for (int i = 0; i < 2; ++i) {
        float4 v = src[t + i * 256];
        s = fmaf(v.x, v.x, s);
        s = fmaf(v.y, v.y, s);
        s = fmaf(v.z, v.z, s);
        s = fmaf(v.w, v.w, s);
        ushort4 o;
        o.x = f2bf(v.x); o.y = f2bf(v.y); o.z = f2bf(v.z); o.w = f2bf(v.w);
        dst[t + i * 256] = o;
    }
#pragma unroll
    for (int off = 32; off >= 1; off >>= 1) s += __shfl_down(s, off, 64);
    __shared__ float red[4];
    if ((t & 63) == 0) red[t >> 6] = s;
    __syncthreads();
    if (t == 0) {
        xx[row] = red[0] + red[1] + red[2] + red[3];
        ap2[row] = 0u;            // float 0.0
        an2[row] = 0x7f7fffffu;   // FLT_MAX
    }
}

// ---------- Kernel 2: triangle 128x128 tiles, m97-style engine, dual-reduction epilogue ----------
#define LDv(p) (*(const bf16x8*)(p))

__global__ __launch_bounds__(256) void gram_tri_kernel(
    const u16* __restrict__ embB, const float* __restrict__ xx,
    const int* __restrict__ lab, unsigned* __restrict__ ap2, unsigned* __restrict__ an2)
{
    __shared__ u16 As[BP * BK];   // 8 KiB, [128 rows][32 cols], 16B-slot swizzled
    __shared__ u16 Bs[BP * BK];   // 8 KiB
    __shared__ int labR[BP], labC[BP];
    __shared__ float xxR[BP], xxC[BP];

    const int tid = threadIdx.x;

    // XCD-aware bijective swizzle (528 = 66 * 8), then triangle unrank (I <= J)
    const int bid = blockIdx.x;
    const int p = (bid & 7) * (NTRI / 8) + (bid >> 3);
    int I = 0, rem = p;
    while (rem >= NPAN - I) { rem -= NPAN - I; ++I; }
    const int J = I + rem;
    const int row0 = I * BP, col0 = J * BP;
    const bool diag = (I == J);

    // ---- staging: linear LDS dest (tid*16B), pre-swizzled global source.
    // Row = 64B = 4 slots; involution: slot ^= (row>>1)&3  (r7-verified, 0 conflicts)
    const int csw = ((tid & 3) ^ ((tid >> 3) & 3)) * 8;   // u16 elements
    const int srow = tid >> 2;                            // 0..63
    const u16* gA0 = embB + (size_t)(row0 + srow) * D_K + csw;
    const u16* gA1 = embB + (size_t)(row0 + 64 + srow) * D_K + csw;
    const u16* gB0 = embB + (size_t)(col0 + srow) * D_K + csw;
    const u16* gB1 = embB + (size_t)(col0 + 64 + srow) * D_K + csw;
    u16* lA = As + tid * 8;
    u16* lB = Bs + tid * 8;

    // ---- fragment constants: 2x2 waves, wave (wr,wc) owns rows wr*64+.., cols wc*64+..
    const int l = tid & 63, w = tid >> 6;
    const int wr = w >> 1, wc = w & 1;
    const int fr = l & 15, fkb = l >> 4;            // frag row / k-slot
    const int kx = (fkb ^ ((fr >> 1) & 3)) * 16;    // swizzled 16B slot within 64B row (bytes)
    const char* AB = (const char*)As;
    const char* BB = (const char*)Bs;
    const int aOff = wr * 4096 + fr * 64;           // + m*1024 (bytes)
    const int bOff = wc * 4096 + fr * 64;           // + n*1024 (bytes)

    f32x4 acc[4][4];
#pragma unroll
    for (int m = 0; m < 4; ++m)
#pragma unroll
        for (int n = 0; n < 4; ++n) acc[m][n] = (f32x4){0.f, 0.f, 0.f, 0.f};

    // ---- m97-style K-loop: stage -> sync (drains vmcnt) -> read frags + 16 MFMA -> sync
    for (int kt = 0; kt < NT; ++kt) {
        const int ko = kt * BK;
        stage16(gA0 + ko, lA); stage16(gA1 + ko, lA + 2048);
        stage16(gB0 + ko, lB); stage16(gB1 + ko, lB + 2048);
        __syncthreads();
        bf16x8 aq[4], bq[4];
#pragma unroll
        for (int m = 0; m < 4; ++m) aq[m] = LDv(AB + aOff + m * 1024 + kx);
#pragma unroll
        for (int n = 0; n < 4; ++n) bq[n] = LDv(BB + bOff + n * 1024 + kx);
#pragma unroll
        for (int m = 0; m < 4; ++m)
#pragma unroll
            for (int n = 0; n < 4; ++n)
                acc[m][n] = __builtin_amdgcn_mfma_f32_16x16x32_bf16(aq[m], bq[n], acc[m][n], 0, 0, 0);
        __syncthreads();
    }

    // ---- epilogue metadata
    if (tid < BP)      { labR[tid] = lab[row0 + tid]; xxR[tid] = xx[row0 + tid]; }
    else               { int u2 = tid - BP; labC[u2] = lab[col0 + u2]; xxC[u2] = xx[col0 + u2]; }
    __syncthreads();

    const int rgrp = l >> 4;

    // ---- ROW pass: output rows = panel I; reduce over this tile's 128 cols
    // C/D: row = m*16 + rgrp*4 + r (+wr*64), col = n*16 + fr (+wc*64)
#pragma unroll
    for (int m = 0; m < 4; ++m) {
#pragma unroll
        for (int r = 0; r < 4; ++r) {
            const int il = wr * 64 + m * 16 + rgrp * 4 + r;
            const int li = labR[il];
            const float xi = xxR[il];
            float apv = 0.f, anv = __FLT_MAX__;
#pragma unroll
            for (int n = 0; n < 4; ++n) {
                const int jl = wc * 64 + n * 16 + fr;
                float d2 = xi + xxC[jl] - 2.f * acc[m][n][r];
                d2 = fmaxf(d2, 1e-12f);
                const bool same = (labC[jl] == li);
                apv = same ? fmaxf(apv, d2) : apv;
                anv = same ? anv : fminf(anv, d2);
            }
#pragma unroll
            for (int off = 1; off < 16; off <<= 1) {   // fold 16 fr-lanes (in-group)
                apv = fmaxf(apv, __shfl_xor(apv, off, 64));
                anv = fminf(anv, __shfl_xor(anv, off, 64));
            }
            if (fr == 0) {
                atomicMax(&ap2[row0 + il], __float_as_uint(apv));
                atomicMin(&an2[row0 + il], __float_as_uint(anv));
            }
        }
    }

    // ---- COL pass (off-diagonal tiles only): output rows = panel J; reduce over tile's 128 rows
    if (!diag) {
#pragma unroll
        for (int n = 0; n < 4; ++n) {
            const int jl = wc * 64 + n * 16 + fr;
            const int lj = labC[jl];
            const float xj = xxC[jl];
            float apv = 0.f, anv = __FLT_MAX__;
#pragma unroll
            for (int m = 0; m < 4; ++m) {
#pragma unroll
                for (int r = 0; r < 4; ++r) {
                    const int il = wr * 64 + m * 16 + rgrp * 4 + r;
                    float d2 = xj + xxR[il] - 2.f * acc[m][n][r];
                    d2 = fmaxf(d2, 1e-12f);
                    const bool same = (labR[il] == lj);
                    apv = same ? fmaxf(apv, d2) : apv;
                    anv = same ? anv : fminf(anv, d2);
                }
            }
            // fold rgrp groups (lanes differ in bits 4-5; fr/col preserved)
            apv = fmaxf(apv, __shfl_xor(apv, 16, 64));
            anv = fminf(anv, __shfl_xor(anv, 16, 64));
            apv = fmaxf(apv, __shfl_xor(apv, 32, 64));
            anv = fminf(anv, __shfl_xor(anv, 32, 64));
            if (rgrp == 0) {   // one lane per col per wave; both wr waves merge via atomics
                atomicMax(&ap2[col0 + jl], __float_as_uint(apv));
                atomicMin(&an2[col0 + jl], __float_as_uint(anv));
            }
        }
    }
}

// ---------- Kernel 3: finalize loss + precision ----------
__global__ __launch_bounds__(256) void finalize_kernel(
    const unsigned* __restrict__ ap2, const unsigned* __restrict__ an2, float* __restrict__ out)
{
    const int t = threadIdx.x;
    float ls = 0.f, ps = 0.f;
    for (int i = t; i < N_ROWS; i += 256) {
        const float ap = sqrtf(__uint_as_float(ap2[i]));
        const float an = sqrtf(__uint_as_float(an2[i]));
        ls += fmaxf(MARGIN - an + ap, 0.f);
        ps += (an > ap) ? 1.f : 0.f;
    }
#pragma unroll
    for (int off = 32; off >= 1; off >>= 1) {
        ls += __shfl_down(ls, off, 64);
        ps += __shfl_down(ps, off, 64);
    }
    __shared__ float rl[4], rp[4];
    if ((t & 63) == 0) { rl[t >> 6] = ls; rp[t >> 6] = ps; }
    __syncthreads();
    if (t == 0) {
        out[0] = (rl[0] + rl[1] + rl[2] + rl[3]) * (1.f / N_ROWS);
        out[1] = (rp[0] + rp[1] + rp[2] + rp[3]) * (1.f / N_ROWS);
    }
}

extern "C" void kernel_launch(void* const* d_in, const int* in_sizes, int n_in,
                              void* d_out, int out_size, void* d_ws, size_t ws_size,
                              hipStream_t stream)
{
    const float* emb = (const float*)d_in[0];
    const int* lab = (const int*)d_in[1];
    float* out = (float*)d_out;

    char* ws = (char*)d_ws;
    u16* embB   = (u16*)ws;                                           // 16 MB
    float* xx   = (float*)(ws + (size_t)N_ROWS * D_K * 2);
    unsigned* ap2 = (unsigned*)(ws + (size_t)N_ROWS * D_K * 2 + N_ROWS * 4);
    unsigned* an2 = (unsigned*)(ws + (size_t)N_ROWS * D_K * 2 + 2 * (size_t)N_ROWS * 4);

    prep_kernel<<<N_ROWS, 256, 0, stream>>>(emb, embB, xx, ap2, an2);
    gram_tri_kernel<<<NTRI, 256, 0, stream>>>(embB, xx, lab, ap2, an2);   // 528 blocks
    finalize_kernel<<<1, 256, 0, stream>>>(ap2, an2, out);
}